// Round 4
// baseline (234.938 us; speedup 1.0000x reference)
//
#include <hip/hip_runtime.h>
#include <math.h>

// Regional Interaction Module — fully fused per-pixel kernel, round 4.
// img: [32,3,512,512] f32, mask: [32,1,512,512] f32, out: [32,3,512,512] f32.
//
// Round-4 experiment: force real memory-level parallelism.
//  - 4 float4-groups per thread, ALL 16 loads issued up front
//  - __builtin_amdgcn_sched_barrier(0) between loads and compute so the
//    compiler cannot sink loads to their use (round 3 came back with
//    VGPR_Count=36 — it had re-sunk everything, only ~4 loads in flight)
//  - __launch_bounds__(256,4): cap 128 VGPRs, >=16 waves/CU
//  - ext_vector float4 throughout (constant-indexable, stays in registers)

#define HW_SHIFT  18             // HW = 512*512 floats per plane
#define HWQ_SHIFT 16             // HW/4 float4 groups per plane
#define HWQ (1 << HWQ_SHIFT)

typedef float vf4 __attribute__((ext_vector_type(4)));

__device__ __forceinline__ float sigm(float x) {
    return __builtin_amdgcn_rcpf(1.0f + __expf(-x));
}

__global__ __launch_bounds__(256, 4) void rim_kernel(
    const float* __restrict__ img,  const float* __restrict__ mask,
    const float* __restrict__ qiw,  const float* __restrict__ qib,
    const float* __restrict__ kiw,  const float* __restrict__ kib,
    const float* __restrict__ viw,  const float* __restrict__ vib,
    const float* __restrict__ qrw,  const float* __restrict__ qrb,
    const float* __restrict__ krw,  const float* __restrict__ krb,
    const float* __restrict__ vrw,  const float* __restrict__ vrb,
    const float* __restrict__ fuw,  const float* __restrict__ fub,
    float* __restrict__ out)
{
    // ---- uniform weight loads (scalar loads -> SGPRs) ----
    const float w_qi0 = qiw[0], w_qi1 = qiw[1], w_qi2 = qiw[2], b_qi = qib[0];
    const float w_ki0 = kiw[0], w_ki1 = kiw[1], w_ki2 = kiw[2], b_ki = kib[0];
    float w_vi[9], b_vi[3];
#pragma unroll
    for (int j = 0; j < 9; ++j) w_vi[j] = viw[j];
#pragma unroll
    for (int j = 0; j < 3; ++j) b_vi[j] = vib[j];
    const float w_qr = qrw[0], b_qr = qrb[0];
    const float w_kr = krw[0], b_kr = krb[0];
    const float w_vr = vrw[0], b_vr = vrb[0];
    float w_fu[18], b_fu[3];
#pragma unroll
    for (int j = 0; j < 18; ++j) w_fu[j] = fuw[j];
#pragma unroll
    for (int j = 0; j < 3; ++j) b_fu[j] = fub[j];

    // Block covers 1024 consecutive float4 groups (16 KB/plane); 1024 | 65536
    // so the whole block sits in one batch plane.
    const int g0 = blockIdx.x * 1024 + threadIdx.x;
    const int b  = g0 >> HWQ_SHIFT;               // batch (wave-uniform)
    const int hw = g0 & (HWQ - 1);

    const vf4* ip = (const vf4*)(img  + ((size_t)b * 3 << HW_SHIFT));
    const vf4* mp = (const vf4*)(mask + ((size_t)b     << HW_SHIFT));

    // ---- 16 loads, all issued before any compute: 256 B/thread in flight ----
    vf4 x0[4], x1[4], x2[4], mq[4];
#pragma unroll
    for (int k = 0; k < 4; ++k) {
        const int h = hw + k * 256;
        x0[k] = ip[h];
        x1[k] = ip[h + HWQ];
        x2[k] = ip[h + 2 * HWQ];
        mq[k] = mp[h];
    }
    __builtin_amdgcn_sched_barrier(0);   // loads may NOT sink below this

    float* op = out + ((size_t)b * 3 << HW_SHIFT);

#pragma unroll
    for (int k = 0; k < 4; ++k) {
        vf4 o0, o1, o2;
#pragma unroll
        for (int l = 0; l < 4; ++l) {
            const float X0 = x0[k][l], X1 = x1[k][l], X2 = x2[k][l], M = mq[k][l];

            const float q_i = b_qi + w_qi0 * X0 + w_qi1 * X1 + w_qi2 * X2;
            const float k_i = b_ki + w_ki0 * X0 + w_ki1 * X1 + w_ki2 * X2;
            const float v0  = b_vi[0] + w_vi[0] * X0 + w_vi[1] * X1 + w_vi[2] * X2;
            const float v1  = b_vi[1] + w_vi[3] * X0 + w_vi[4] * X1 + w_vi[5] * X2;
            const float v2  = b_vi[2] + w_vi[6] * X0 + w_vi[7] * X1 + w_vi[8] * X2;
            const float q_r = b_qr + w_qr * M;
            const float k_r = b_kr + w_kr * M;
            const float v_r = b_vr + w_vr * M;

            const float s_ii = sigm(q_i * k_i);
            const float s_ir = sigm(q_i * k_r);
            const float s_rr = sigm(q_r * k_r);
            const float s_ri = sigm(q_r * k_i);

            const float fi0 = s_ii * v0 + s_ir * v_r;
            const float fi1 = s_ii * v1 + s_ir * v_r;
            const float fi2 = s_ii * v2 + s_ir * v_r;
            const float fr0 = s_rr * v_r + s_ri * v0;
            const float fr1 = s_rr * v_r + s_ri * v1;
            const float fr2 = s_rr * v_r + s_ri * v2;

            o0[l] = b_fu[0] + w_fu[0]  * fi0 + w_fu[1]  * fi1 + w_fu[2]  * fi2
                            + w_fu[3]  * fr0 + w_fu[4]  * fr1 + w_fu[5]  * fr2;
            o1[l] = b_fu[1] + w_fu[6]  * fi0 + w_fu[7]  * fi1 + w_fu[8]  * fi2
                            + w_fu[9]  * fr0 + w_fu[10] * fr1 + w_fu[11] * fr2;
            o2[l] = b_fu[2] + w_fu[12] * fi0 + w_fu[13] * fi1 + w_fu[14] * fi2
                            + w_fu[15] * fr0 + w_fu[16] * fr1 + w_fu[17] * fr2;
        }
        const int h = hw + k * 256;
        __builtin_nontemporal_store(o0, (vf4*)(op + 4 * (size_t)h));
        __builtin_nontemporal_store(o1, (vf4*)(op + 4 * ((size_t)h + HWQ)));
        __builtin_nontemporal_store(o2, (vf4*)(op + 4 * ((size_t)h + 2 * HWQ)));
    }
}

extern "C" void kernel_launch(void* const* d_in, const int* in_sizes, int n_in,
                              void* d_out, int out_size, void* d_ws, size_t ws_size,
                              hipStream_t stream) {
    const float* img  = (const float*)d_in[0];
    const float* mask = (const float*)d_in[1];
    const float* qiw  = (const float*)d_in[2];
    const float* qib  = (const float*)d_in[3];
    const float* kiw  = (const float*)d_in[4];
    const float* kib  = (const float*)d_in[5];
    const float* viw  = (const float*)d_in[6];
    const float* vib  = (const float*)d_in[7];
    const float* qrw  = (const float*)d_in[8];
    const float* qrb  = (const float*)d_in[9];
    const float* krw  = (const float*)d_in[10];
    const float* krb  = (const float*)d_in[11];
    const float* vrw  = (const float*)d_in[12];
    const float* vrb  = (const float*)d_in[13];
    const float* fuw  = (const float*)d_in[14];
    const float* fub  = (const float*)d_in[15];
    float* out = (float*)d_out;

    // 2,097,152 float4 groups; 4 per thread -> 524,288 threads =
    // 2048 blocks x 256 (exact fit, no bounds check).
    rim_kernel<<<2048, 256, 0, stream>>>(img, mask, qiw, qib, kiw, kib, viw, vib,
                                         qrw, qrb, krw, krb, vrw, vrb, fuw, fub, out);
}